// Round 3
// baseline (432.526 us; speedup 1.0000x reference)
//
#include <hip/hip_runtime.h>
#include <stdint.h>

#define ALPHA 0.2f

typedef __attribute__((ext_vector_type(8))) short s16x8;
typedef __attribute__((ext_vector_type(4))) float f32x4;

__device__ __forceinline__ unsigned short f2bf(float f) {
    union { float f; unsigned u; } c; c.f = f;
    unsigned u = c.u;
    u += 0x7fffu + ((u >> 16) & 1u);
    return (unsigned short)(u >> 16);
}
__device__ __forceinline__ float bf2f(unsigned short u) {
    union { unsigned u; float f; } c; c.u = ((unsigned)u) << 16;
    return c.f;
}

// ---- prep: wT bf16 [c=256][f=256] (c=(h,e)) + wa1/wa2 = W@a1, W@a2 (fp32) ----
__global__ void k_prep_w(const float* __restrict__ weight, const float* __restrict__ att,
                         unsigned short* __restrict__ wT, float* __restrict__ wa1,
                         float* __restrict__ wa2) {
    int blk = blockIdx.x, t = threadIdx.x;
    if (blk < 256) {
        int c = blk, h = c >> 5, e = c & 31;
        wT[c * 256 + t] = f2bf(weight[h * 8192 + t * 32 + e]);
    } else {
        int id = blk - 256, h = id >> 1, which = id & 1;
        float s = 0.f;
        for (int e = 0; e < 32; ++e)
            s += weight[h * 8192 + t * 32 + e] * att[h * 64 + which * 32 + e];
        (which ? wa2 : wa1)[h * 256 + t] = s;
    }
}

// ---- s1,s2 fp32 exact-score path: s1 = x @ (W@a1) ----
__global__ void k_prep_s(const float* __restrict__ x, const float* __restrict__ wa1,
                         const float* __restrict__ wa2, float* __restrict__ s1,
                         float* __restrict__ s2) {
    __shared__ float xs[256];
    int bm = blockIdx.x, t = threadIdx.x;
    xs[t] = x[bm * 256 + t];
    __syncthreads();
    int lane16 = t & 15, grp = t >> 4;
    int h = grp >> 1, which = grp & 1;
    const float* wap = (which ? wa2 : wa1) + h * 256;
    float s = 0.f;
    for (int f = lane16; f < 256; f += 16) s += xs[f] * wap[f];
    s += __shfl_xor(s, 8); s += __shfl_xor(s, 4);
    s += __shfl_xor(s, 2); s += __shfl_xor(s, 1);
    if (lane16 == 0) {
        int b = bm >> 10, m = bm & 1023;
        (which ? s2 : s1)[(b * 8 + h) * 1024 + m] = s;
    }
}

// ---- WhT[(b,h,e)][m] bf16 via pure VALU (diagnostic: no MFMA) ----
__global__ void __launch_bounds__(256) k_wht(const unsigned short* __restrict__ wT,
                                             const float* __restrict__ x,
                                             unsigned short* __restrict__ WhT) {
    __shared__ float xs[16][256];
    int blk = blockIdx.x, t = threadIdx.x;
    int b = blk >> 6, m0 = (blk & 63) * 16;
    for (int i = t; i < 4096; i += 256)
        xs[i >> 8][i & 255] = x[(b * 1024 + m0 + (i >> 8)) * 256 + (i & 255)];
    __syncthreads();
    float acc[16];
#pragma unroll
    for (int m = 0; m < 16; ++m) acc[m] = 0.f;
    const unsigned short* wr = wT + t * 256;          // t = c = h*32+e
    for (int f0 = 0; f0 < 256; f0 += 8) {
        s16x8 wv = *(const s16x8*)(wr + f0);
#pragma unroll
        for (int u = 0; u < 8; ++u) {
            float wf = bf2f((unsigned short)wv[u]);
#pragma unroll
            for (int m = 0; m < 16; ++m) acc[m] += wf * xs[m][f0 + u];
        }
    }
    s16x8 o0, o1;
#pragma unroll
    for (int m = 0; m < 8; ++m) {
        o0[m] = (short)f2bf(acc[m]);
        o1[m] = (short)f2bf(acc[8 + m]);
    }
    unsigned short* dst = WhT + (b * 256 + t) * 1024 + m0;   // (b*8+h)*32+e == b*256+t
    *(s16x8*)dst = o0;
    *(s16x8*)(dst + 8) = o1;
}

// ---- attention: pure-VALU PV; fp32 output (reference output dtype is float32) ----
__global__ void __launch_bounds__(256) k_attn(const int* __restrict__ adj,
                                              const float* __restrict__ s1,
                                              const float* __restrict__ s2,
                                              const unsigned short* __restrict__ WhT,
                                              float* __restrict__ out) {
    __shared__ unsigned long long amask[16][16];
    __shared__ float s2s[8][1024];
    __shared__ float s1s[8][16];
    __shared__ unsigned short WhL[4][64][32];   // per-wave chunk of Wh[n][e]
    int blk = blockIdx.x, t = threadIdx.x;
    int b = blk >> 6, m0 = (blk & 63) * 16;
    int w = t >> 6, l = t & 63;
    for (int i = t; i < 8192; i += 256) s2s[i >> 10][i & 1023] = s2[b * 8192 + i];
    if (t < 128) s1s[t >> 4][t & 15] = s1[b * 8192 + (t >> 4) * 1024 + m0 + (t & 15)];
#pragma unroll
    for (int rr = 0; rr < 4; ++rr) {
        int row = rr * 4 + w;
#pragma unroll
        for (int ch = 0; ch < 16; ++ch) {
            int val = adj[(b * 1024 + m0 + row) * 1024 + ch * 64 + l];
            unsigned long long mk = __ballot(val > 0);
            if (l == 0) amask[row][ch] = mk;
        }
    }
    __syncthreads();
    int m = l & 15, eg = l >> 4;   // lane owns output row m, e-range [eg*8, eg*8+8)
    for (int hh = 0; hh < 2; ++hh) {
        int h = w + hh * 4;
        float s1v = s1s[h][m];
        // pass A: masked row max (lanes partition n by eg)
        float mx = -3.0e38f;
        for (int i = 0; i < 4; ++i) {
            unsigned long long wm = amask[m][eg * 4 + i];
            int nbase = eg * 256 + i * 64;
            for (int jj = 0; jj < 64; ++jj) {
                float sc = s1v + s2s[h][nbase + jj];
                sc = sc > 0.f ? sc : ALPHA * sc;
                if ((wm >> jj) & 1) mx = fmaxf(mx, sc);
            }
        }
        mx = fmaxf(mx, __shfl_xor(mx, 16));
        mx = fmaxf(mx, __shfl_xor(mx, 32));
        // pass B: every lane walks ALL n; accumulates its 8 e-columns
        float acc[8];
#pragma unroll
        for (int j = 0; j < 8; ++j) acc[j] = 0.f;
        float rsum = 0.f;
        const unsigned short* whb = WhT + (b * 8 + h) * 32768;
        for (int c0 = 0; c0 < 1024; c0 += 64) {
            // stage Wh[c0:c0+64][0:32] into this wave's WhL slice (transposed)
            for (int i = l; i < 256; i += 64) {
                int e = i >> 3, n = (i & 7) * 8;
                s16x8 v = *(const s16x8*)(whb + e * 1024 + c0 + n);
#pragma unroll
                for (int u = 0; u < 8; ++u) WhL[w][n + u][e] = (unsigned short)v[u];
            }
            __syncthreads();
            unsigned long long wm = amask[m][c0 >> 6];
            for (int n = 0; n < 64; ++n) {
                float sc = s1v + s2s[h][c0 + n];
                sc = sc > 0.f ? sc : ALPHA * sc;
                float p = ((wm >> n) & 1) ? __expf(sc - mx) : 0.f;
                rsum += p;
                s16x8 wv = *(const s16x8*)&WhL[w][n][eg * 8];
#pragma unroll
                for (int j = 0; j < 8; ++j) acc[j] += p * bf2f((unsigned short)wv[j]);
            }
            __syncthreads();
        }
        float inv = 1.f / rsum;
        f32x4 o0, o1;
#pragma unroll
        for (int j = 0; j < 8; ++j) {
            float v = acc[j] * inv;
            v = v > 0.f ? v : __expf(v) - 1.f;
            if (j < 4) o0[j] = v; else o1[j - 4] = v;
        }
        float* op = &out[(b * 1024 + m0 + m) * 256 + h * 32 + eg * 8];
        *(f32x4*)op = o0;
        *(f32x4*)(op + 4) = o1;
    }
}

extern "C" void kernel_launch(void* const* d_in, const int* in_sizes, int n_in,
                              void* d_out, int out_size, void* d_ws, size_t ws_size,
                              hipStream_t stream) {
    const float* x      = (const float*)d_in[0];
    const int*   adj    = (const int*)d_in[1];
    const float* weight = (const float*)d_in[2];
    const float* att    = (const float*)d_in[3];

    char* ws = (char*)d_ws;
    unsigned short* wT  = (unsigned short*)(ws);            // 256*256*2 = 128K
    unsigned short* WhT = (unsigned short*)(ws + 131072);   // 2M*2      = 4M
    float* s1  = (float*)(ws + 4325376);                    // 64K*4
    float* s2  = (float*)(ws + 4587520);                    // 64K*4
    float* wa1 = (float*)(ws + 4849664);                    // 2K*4
    float* wa2 = (float*)(ws + 4857856);                    // 2K*4  (end ~4.87MB)
    float* out = (float*)d_out;

    k_prep_w<<<272, 256, 0, stream>>>(weight, att, wT, wa1, wa2);
    k_prep_s<<<8192, 256, 0, stream>>>(x, wa1, wa2, s1, s2);
    k_wht<<<512, 256, 0, stream>>>(wT, x, WhT);
    k_attn<<<512, 256, 0, stream>>>(adj, s1, s2, WhT, out);
}

// Round 6
// 84.489 us; speedup vs baseline: 5.1193x; 5.1193x over previous
//
#include <hip/hip_runtime.h>
#include <stdint.h>

#define ALPHA 0.2f

typedef __attribute__((ext_vector_type(8))) short s16x8;
typedef __attribute__((ext_vector_type(4))) float f32x4;
typedef __attribute__((ext_vector_type(4))) unsigned u32x4;

__device__ __forceinline__ unsigned short f2bf(float f) {
    union { float f; unsigned u; } c; c.f = f;
    unsigned u = c.u;
    u += 0x7fffu + ((u >> 16) & 1u);
    return (unsigned short)(u >> 16);
}

// ---- prep: wT bf16 [c=256][f=256] (c=(h,e)) + wa1/wa2 = W@a1, W@a2 (fp32) ----
__global__ void k_prep_w(const float* __restrict__ weight, const float* __restrict__ att,
                         unsigned short* __restrict__ wT, float* __restrict__ wa1,
                         float* __restrict__ wa2) {
    int blk = blockIdx.x, t = threadIdx.x;
    if (blk < 256) {
        int c = blk, h = c >> 5, e = c & 31;
        wT[c * 256 + t] = f2bf(weight[h * 8192 + t * 32 + e]);
    } else {
        int id = blk - 256, h = id >> 1, which = id & 1;
        float s = 0.f;
        for (int e = 0; e < 32; ++e)
            s += weight[h * 8192 + t * 32 + e] * att[h * 64 + which * 32 + e];
        (which ? wa2 : wa1)[h * 256 + t] = s;
    }
}

// ---- s1,s2 fp32 exact-score path (s1 = x @ (W@a1)) + x16 bf16 copy ----
__global__ void k_prep_s(const float* __restrict__ x, const float* __restrict__ wa1,
                         const float* __restrict__ wa2, float* __restrict__ s1,
                         float* __restrict__ s2, unsigned short* __restrict__ x16) {
    __shared__ float xs[256];
    int bm = blockIdx.x, t = threadIdx.x;
    float xv = x[bm * 256 + t];
    xs[t] = xv;
    x16[bm * 256 + t] = f2bf(xv);
    __syncthreads();
    int lane16 = t & 15, grp = t >> 4;
    int h = grp >> 1, which = grp & 1;
    const float* wap = (which ? wa2 : wa1) + h * 256;
    float s = 0.f;
    for (int f = lane16; f < 256; f += 16) s += xs[f] * wap[f];
    s += __shfl_xor(s, 8); s += __shfl_xor(s, 4);
    s += __shfl_xor(s, 2); s += __shfl_xor(s, 1);
    if (lane16 == 0) {
        int b = bm >> 10, m = bm & 1023;
        (which ? s2 : s1)[(b * 8 + h) * 1024 + m] = s;
    }
}

// ---- WhT[(b,h,e)][m] bf16 = (x@W)^T via MFMA (A=wT rows c, B=x^T cols m) ----
__global__ void k_wht(const unsigned short* __restrict__ wT,
                      const unsigned short* __restrict__ x16,
                      unsigned short* __restrict__ WhT) {
    int t = threadIdx.x;
    int W = blockIdx.x * 4 + (t >> 6);
    int l = t & 63;
    int b = W >> 8, r = W & 255;
    int c0 = (r >> 4) * 16, m0 = (r & 15) * 64;
    int lrow = l & 15, lk = l >> 4;
    f32x4 acc[4] = {{0,0,0,0},{0,0,0,0},{0,0,0,0},{0,0,0,0}};
    const unsigned short* ap = wT + (c0 + lrow) * 256 + lk * 8;
    const unsigned short* bp = x16 + (b * 1024 + m0 + lrow) * 256 + lk * 8;
    for (int k0 = 0; k0 < 256; k0 += 32) {
        s16x8 af = *(const s16x8*)(ap + k0);
#pragma unroll
        for (int t4 = 0; t4 < 4; ++t4) {
            s16x8 bf = *(const s16x8*)(bp + t4 * 16 * 256 + k0);
            acc[t4] = __builtin_amdgcn_mfma_f32_16x16x32_bf16(af, bf, acc[t4], 0, 0, 0);
        }
    }
#pragma unroll
    for (int t4 = 0; t4 < 4; ++t4)
#pragma unroll
        for (int j = 0; j < 4; ++j) {
            int c = c0 + lk * 4 + j;                 // D row
            int m = m0 + t4 * 16 + lrow;             // D col
            WhT[(b * 256 + c) * 1024 + m] = f2bf(acc[t4][j]);
        }
}

// ---- attention: 8 waves/block, 1 head/wave, MFMA PV, masked shift, inf-free ----
__global__ void __launch_bounds__(512) k_attn(const int* __restrict__ adj,
                                              const float* __restrict__ s1,
                                              const float* __restrict__ s2,
                                              const unsigned short* __restrict__ WhT,
                                              float* __restrict__ out) {
    __shared__ unsigned amaskw[16][33];
    __shared__ float s2s[8][1024];
    __shared__ float s1s[8][16];
    int blk = blockIdx.x, t = threadIdx.x;
    int b = blk >> 6, m0 = (blk & 63) * 16;
    int w = t >> 6, l = t & 63;
    for (int i = t; i < 8192; i += 512) s2s[i >> 10][i & 1023] = s2[b * 8192 + i];
    if (t < 128) s1s[t >> 4][t & 15] = s1[b * 8192 + (t >> 4) * 1024 + m0 + (t & 15)];
#pragma unroll
    for (int rr = 0; rr < 2; ++rr) {
        int row = rr * 8 + w;
#pragma unroll
        for (int ch = 0; ch < 16; ++ch) {
            int val = adj[(b * 1024 + m0 + row) * 1024 + ch * 64 + l];
            unsigned long long mk = __ballot(val > 0);
            if (l == 0) {
                amaskw[row][ch * 2] = (unsigned)mk;
                amaskw[row][ch * 2 + 1] = (unsigned)(mk >> 32);
            }
        }
    }
    __syncthreads();
    int m = l & 15, q = l >> 4;
    int h = w;
    float s1v = s1s[h][m];
    // pass A: MASKED row-max of s2 (leaky monotone => mx = leaky(s1v + max))
    float mxs2 = -3.0e38f;
    for (int n0 = 0; n0 < 1024; n0 += 32) {
        unsigned wm8 = amaskw[m][n0 >> 5] >> (q * 8);
        int nn = n0 + q * 8;
        f32x4 svA = *(const f32x4*)&s2s[h][nn];
        f32x4 svB = *(const f32x4*)&s2s[h][nn + 4];
#pragma unroll
        for (int u = 0; u < 8; ++u) {
            float sv = (u < 4 ? svA[u] : svB[u - 4]);
            float cand = ((wm8 >> u) & 1u) ? sv : -3.0e38f;
            mxs2 = fmaxf(mxs2, cand);
        }
    }
    mxs2 = fmaxf(mxs2, __shfl_xor(mxs2, 16));
    mxs2 = fmaxf(mxs2, __shfl_xor(mxs2, 32));
    float mxr = s1v + mxs2;
    float mx = fmaxf(mxr, ALPHA * mxr);
    // pass B: P = exp(min(leaky(s)-mx,0)) * bit  (clamp keeps e finite so e*0==0;
    // unmasked scores can exceed the masked max by >88 -> expf inf -> inf*0=NaN, r5 bug)
    f32x4 acc0 = {0,0,0,0}, acc1 = {0,0,0,0};
    float rsum = 0.f;
    const unsigned short* whb = WhT + (b * 8 + h) * 32768;
    const unsigned short* bp0 = whb + m * 1024 + q * 8;
    const unsigned short* bp1 = whb + (16 + m) * 1024 + q * 8;
    for (int n0 = 0; n0 < 1024; n0 += 32) {
        unsigned wm8 = amaskw[m][n0 >> 5] >> (q * 8);
        int nn = n0 + q * 8;
        f32x4 svA = *(const f32x4*)&s2s[h][nn];
        f32x4 svB = *(const f32x4*)&s2s[h][nn + 4];
        float pv[8];
#pragma unroll
        for (int u = 0; u < 8; ++u) {
            float sc = s1v + (u < 4 ? svA[u] : svB[u - 4]);
            float lk = fmaxf(sc, ALPHA * sc);
            float e = __expf(fminf(lk - mx, 0.f));
            float bitf = (float)((wm8 >> u) & 1u);
            pv[u] = e * bitf;
            rsum += pv[u];
        }
        u32x4 aw;
#pragma unroll
        for (int p = 0; p < 4; ++p) {
            union { float f; unsigned u; } lo, hi;
            lo.f = pv[2 * p]; hi.f = pv[2 * p + 1];
            aw[p] = __builtin_amdgcn_perm(hi.u, lo.u, 0x07060302u);  // truncate-pack 2xbf16
        }
        s16x8 af = __builtin_bit_cast(s16x8, aw);
        s16x8 bf0 = *(const s16x8*)(bp0 + n0);
        s16x8 bf1 = *(const s16x8*)(bp1 + n0);
        acc0 = __builtin_amdgcn_mfma_f32_16x16x32_bf16(af, bf0, acc0, 0, 0, 0);
        acc1 = __builtin_amdgcn_mfma_f32_16x16x32_bf16(af, bf1, acc1, 0, 0, 0);
    }
    rsum += __shfl_xor(rsum, 16);
    rsum += __shfl_xor(rsum, 32);
#pragma unroll
    for (int j = 0; j < 4; ++j) {
        int mrow = q * 4 + j;
        float rs = __shfl(rsum, mrow);
        float inv = 1.f / rs;
        float v0 = acc0[j] * inv;
        float v1 = acc1[j] * inv;
        v0 = v0 > 0.f ? v0 : __expf(v0) - 1.f;
        v1 = v1 > 0.f ? v1 : __expf(v1) - 1.f;
        float* op = &out[(b * 1024 + m0 + mrow) * 256 + h * 32];
        op[m] = v0;
        op[16 + m] = v1;
    }
}

extern "C" void kernel_launch(void* const* d_in, const int* in_sizes, int n_in,
                              void* d_out, int out_size, void* d_ws, size_t ws_size,
                              hipStream_t stream) {
    const float* x      = (const float*)d_in[0];
    const int*   adj    = (const int*)d_in[1];
    const float* weight = (const float*)d_in[2];
    const float* att    = (const float*)d_in[3];

    char* ws = (char*)d_ws;
    unsigned short* wT  = (unsigned short*)(ws);             // 128K
    unsigned short* x16 = (unsigned short*)(ws + 131072);    // 4M
    unsigned short* WhT = (unsigned short*)(ws + 4325376);   // 4M
    float* s1  = (float*)(ws + 8519680);                     // 256K
    float* s2  = (float*)(ws + 8781824);                     // 256K
    float* wa1 = (float*)(ws + 9043968);                     // 8K
    float* wa2 = (float*)(ws + 9052160);                     // 8K
    float* out = (float*)d_out;

    k_prep_w<<<272, 256, 0, stream>>>(weight, att, wT, wa1, wa2);
    k_prep_s<<<8192, 256, 0, stream>>>(x, wa1, wa2, s1, s2, x16);
    k_wht<<<512, 256, 0, stream>>>(wT, x16, WhT);
    k_attn<<<512, 512, 0, stream>>>(adj, s1, s2, WhT, out);
}

// Round 7
// 82.876 us; speedup vs baseline: 5.2190x; 1.0195x over previous
//
#include <hip/hip_runtime.h>
#include <stdint.h>

#define ALPHA 0.2f

typedef __attribute__((ext_vector_type(8))) short s16x8;
typedef __attribute__((ext_vector_type(4))) float f32x4;
typedef __attribute__((ext_vector_type(4))) unsigned u32x4;

__device__ __forceinline__ unsigned short f2bf(float f) {
    union { float f; unsigned u; } c; c.f = f;
    unsigned u = c.u;
    u += 0x7fffu + ((u >> 16) & 1u);
    return (unsigned short)(u >> 16);
}

// ---- prep: wT bf16 [c=256][f=256] (c=(h,e)) + wa1/wa2 = W@a1, W@a2 (fp32) ----
__global__ void k_prep_w(const float* __restrict__ weight, const float* __restrict__ att,
                         unsigned short* __restrict__ wT, float* __restrict__ wa1,
                         float* __restrict__ wa2) {
    int blk = blockIdx.x, t = threadIdx.x;
    if (blk < 256) {
        int c = blk, h = c >> 5, e = c & 31;
        wT[c * 256 + t] = f2bf(weight[h * 8192 + t * 32 + e]);
    } else {
        int id = blk - 256, h = id >> 1, which = id & 1;
        float s = 0.f;
        for (int e = 0; e < 32; ++e)
            s += weight[h * 8192 + t * 32 + e] * att[h * 64 + which * 32 + e];
        (which ? wa2 : wa1)[h * 256 + t] = s;
    }
}

// ---- s1,s2 fp32 exact-score path (s1 = x @ (W@a1)) + x16 bf16 copy ----
__global__ void k_prep_s(const float* __restrict__ x, const float* __restrict__ wa1,
                         const float* __restrict__ wa2, float* __restrict__ s1,
                         float* __restrict__ s2, unsigned short* __restrict__ x16) {
    __shared__ float xs[256];
    int bm = blockIdx.x, t = threadIdx.x;
    float xv = x[bm * 256 + t];
    xs[t] = xv;
    x16[bm * 256 + t] = f2bf(xv);
    __syncthreads();
    int lane16 = t & 15, grp = t >> 4;
    int h = grp >> 1, which = grp & 1;
    const float* wap = (which ? wa2 : wa1) + h * 256;
    float s = 0.f;
    for (int f = lane16; f < 256; f += 16) s += xs[f] * wap[f];
    s += __shfl_xor(s, 8); s += __shfl_xor(s, 4);
    s += __shfl_xor(s, 2); s += __shfl_xor(s, 1);
    if (lane16 == 0) {
        int b = bm >> 10, m = bm & 1023;
        (which ? s2 : s1)[(b * 8 + h) * 1024 + m] = s;
    }
}

// ---- adj (32MB int) -> packed bitmask (1MB), streaming at HBM rate ----
__global__ void k_mask(const int* __restrict__ adj, unsigned* __restrict__ gmask) {
    int t = threadIdx.x, w = t >> 6, l = t & 63;
    int wid = blockIdx.x * 4 + w;           // 32768 waves total
#pragma unroll
    for (int i = 0; i < 4; ++i) {
        int c = wid * 4 + i;                // chunk of 64 columns; flat offset c*64+l
        int val = adj[c * 64 + l];
        unsigned long long mk = __ballot(val > 0);
        if (l == 0) {
            gmask[c * 2]     = (unsigned)mk;
            gmask[c * 2 + 1] = (unsigned)(mk >> 32);
        }
    }
}

// ---- WhT[(b,h,e)][m] bf16 = (x@W)^T via MFMA (A=wT rows c, B=x^T cols m) ----
__global__ void k_wht(const unsigned short* __restrict__ wT,
                      const unsigned short* __restrict__ x16,
                      unsigned short* __restrict__ WhT) {
    int t = threadIdx.x;
    int W = blockIdx.x * 4 + (t >> 6);
    int l = t & 63;
    int b = W >> 8, r = W & 255;
    int c0 = (r >> 4) * 16, m0 = (r & 15) * 64;
    int lrow = l & 15, lk = l >> 4;
    f32x4 acc[4] = {{0,0,0,0},{0,0,0,0},{0,0,0,0},{0,0,0,0}};
    const unsigned short* ap = wT + (c0 + lrow) * 256 + lk * 8;
    const unsigned short* bp = x16 + (b * 1024 + m0 + lrow) * 256 + lk * 8;
    for (int k0 = 0; k0 < 256; k0 += 32) {
        s16x8 af = *(const s16x8*)(ap + k0);
#pragma unroll
        for (int t4 = 0; t4 < 4; ++t4) {
            s16x8 bf = *(const s16x8*)(bp + t4 * 16 * 256 + k0);
            acc[t4] = __builtin_amdgcn_mfma_f32_16x16x32_bf16(af, bf, acc[t4], 0, 0, 0);
        }
    }
#pragma unroll
    for (int t4 = 0; t4 < 4; ++t4)
#pragma unroll
        for (int j = 0; j < 4; ++j) {
            int c = c0 + lk * 4 + j;                 // D row
            int m = m0 + t4 * 16 + lrow;             // D col
            WhT[(b * 256 + c) * 1024 + m] = f2bf(acc[t4][j]);
        }
}

// ---- attention: grid 1024 (b, mtile16, headgroup4), 4 waves = 4 heads ----
__global__ void __launch_bounds__(256) k_attn(const unsigned* __restrict__ gmask,
                                              const float* __restrict__ s1,
                                              const float* __restrict__ s2,
                                              const unsigned short* __restrict__ WhT,
                                              float* __restrict__ out) {
    __shared__ unsigned amaskw[16][33];
    __shared__ float s2s[4][1024];
    __shared__ float s1s[4][16];
    int bid = blockIdx.x;
    int o = (bid & 7) * 128 + (bid >> 3);   // XCD swizzle: each XCD owns one b
    int b = o >> 7, r = o & 127;
    int m0 = (r >> 1) * 16, hg = (r & 1) * 4;
    int t = threadIdx.x, w = t >> 6, l = t & 63;
    for (int i = t; i < 4096; i += 256)
        s2s[i >> 10][i & 1023] = s2[b * 8192 + (hg + (i >> 10)) * 1024 + (i & 1023)];
    if (t < 64) s1s[t >> 4][t & 15] = s1[b * 8192 + (hg + (t >> 4)) * 1024 + m0 + (t & 15)];
    for (int i = t; i < 512; i += 256)
        amaskw[i >> 5][i & 31] = gmask[(b * 1024 + m0) * 32 + i];
    __syncthreads();
    int m = l & 15, q = l >> 4;
    int h = hg + w;
    float s1v = s1s[w][m];
    // pass A: MASKED row-max of s2 (leaky monotone => mx = leaky(s1v + max))
    float mxs2 = -3.0e38f;
    for (int n0 = 0; n0 < 1024; n0 += 32) {
        unsigned wm8 = amaskw[m][n0 >> 5] >> (q * 8);
        int nn = n0 + q * 8;
        f32x4 svA = *(const f32x4*)&s2s[w][nn];
        f32x4 svB = *(const f32x4*)&s2s[w][nn + 4];
#pragma unroll
        for (int u = 0; u < 8; ++u) {
            float sv = (u < 4 ? svA[u] : svB[u - 4]);
            float cand = ((wm8 >> u) & 1u) ? sv : -3.0e38f;
            mxs2 = fmaxf(mxs2, cand);
        }
    }
    mxs2 = fmaxf(mxs2, __shfl_xor(mxs2, 16));
    mxs2 = fmaxf(mxs2, __shfl_xor(mxs2, 32));
    float mxr = s1v + mxs2;
    float mx = fmaxf(mxr, ALPHA * mxr);
    // pass B: arg = bit ? lk-mx : -inf  (exp(-inf)=0; masked-in => arg<=0, no inf)
    f32x4 acc0 = {0,0,0,0}, acc1 = {0,0,0,0};
    float rsum = 0.f;
    const unsigned short* whb = WhT + (b * 8 + h) * 32768;
    const unsigned short* bp0 = whb + m * 1024 + q * 8;
    const unsigned short* bp1 = whb + (16 + m) * 1024 + q * 8;
    for (int n0 = 0; n0 < 1024; n0 += 32) {
        unsigned wm8 = amaskw[m][n0 >> 5] >> (q * 8);
        int nn = n0 + q * 8;
        f32x4 svA = *(const f32x4*)&s2s[w][nn];
        f32x4 svB = *(const f32x4*)&s2s[w][nn + 4];
        float pv[8];
#pragma unroll
        for (int u = 0; u < 8; ++u) {
            float sc = s1v + (u < 4 ? svA[u] : svB[u - 4]);
            float lk = fmaxf(sc, ALPHA * sc);
            float arg = ((wm8 >> u) & 1u) ? (lk - mx) : -3.0e38f;
            pv[u] = __expf(arg);
            rsum += pv[u];
        }
        u32x4 aw;
#pragma unroll
        for (int p = 0; p < 4; ++p) {
            union { float f; unsigned u; } lo, hi;
            lo.f = pv[2 * p]; hi.f = pv[2 * p + 1];
            aw[p] = __builtin_amdgcn_perm(hi.u, lo.u, 0x07060302u);  // truncate-pack 2xbf16
        }
        s16x8 af = __builtin_bit_cast(s16x8, aw);
        s16x8 bf0 = *(const s16x8*)(bp0 + n0);
        s16x8 bf1 = *(const s16x8*)(bp1 + n0);
        acc0 = __builtin_amdgcn_mfma_f32_16x16x32_bf16(af, bf0, acc0, 0, 0, 0);
        acc1 = __builtin_amdgcn_mfma_f32_16x16x32_bf16(af, bf1, acc1, 0, 0, 0);
    }
    rsum += __shfl_xor(rsum, 16);
    rsum += __shfl_xor(rsum, 32);
#pragma unroll
    for (int j = 0; j < 4; ++j) {
        int mrow = q * 4 + j;
        float rs = __shfl(rsum, mrow);
        float inv = 1.f / rs;
        float v0 = acc0[j] * inv;
        float v1 = acc1[j] * inv;
        v0 = v0 > 0.f ? v0 : __expf(v0) - 1.f;
        v1 = v1 > 0.f ? v1 : __expf(v1) - 1.f;
        float* op = &out[(b * 1024 + m0 + mrow) * 256 + h * 32];
        op[m] = v0;
        op[16 + m] = v1;
    }
}

extern "C" void kernel_launch(void* const* d_in, const int* in_sizes, int n_in,
                              void* d_out, int out_size, void* d_ws, size_t ws_size,
                              hipStream_t stream) {
    const float* x      = (const float*)d_in[0];
    const int*   adj    = (const int*)d_in[1];
    const float* weight = (const float*)d_in[2];
    const float* att    = (const float*)d_in[3];

    char* ws = (char*)d_ws;
    unsigned short* wT  = (unsigned short*)(ws);             // 128K
    unsigned short* x16 = (unsigned short*)(ws + 131072);    // 4M
    unsigned short* WhT = (unsigned short*)(ws + 4325376);   // 4M
    float* s1  = (float*)(ws + 8519680);                     // 256K
    float* s2  = (float*)(ws + 8781824);                     // 256K
    float* wa1 = (float*)(ws + 9043968);                     // 8K
    float* wa2 = (float*)(ws + 9052160);                     // 8K
    unsigned* gmask = (unsigned*)(ws + 9060352);             // 1M  (end ~10.1MB)
    float* out = (float*)d_out;

    k_prep_w<<<272, 256, 0, stream>>>(weight, att, wT, wa1, wa2);
    k_prep_s<<<8192, 256, 0, stream>>>(x, wa1, wa2, s1, s2, x16);
    k_mask<<<8192, 256, 0, stream>>>(adj, gmask);
    k_wht<<<512, 256, 0, stream>>>(wT, x16, WhT);
    k_attn<<<1024, 256, 0, stream>>>(gmask, s1, s2, WhT, out);
}

// Round 8
// 82.624 us; speedup vs baseline: 5.2348x; 1.0030x over previous
//
#include <hip/hip_runtime.h>
#include <stdint.h>

#define ALPHA 0.2f
#define LOG2E 1.44269504089f

typedef __attribute__((ext_vector_type(8))) short s16x8;
typedef __attribute__((ext_vector_type(4))) float f32x4;
typedef __attribute__((ext_vector_type(4))) unsigned u32x4;

__device__ __forceinline__ unsigned short f2bf(float f) {
    union { float f; unsigned u; } c; c.f = f;
    unsigned u = c.u;
    u += 0x7fffu + ((u >> 16) & 1u);
    return (unsigned short)(u >> 16);
}

// ---- prep: wT bf16 [c=256][f=256] (c=(h,e)) + wa1/wa2 = log2e * W@a{1,2} ----
__global__ void k_prep_w(const float* __restrict__ weight, const float* __restrict__ att,
                         unsigned short* __restrict__ wT, float* __restrict__ wa1,
                         float* __restrict__ wa2) {
    int blk = blockIdx.x, t = threadIdx.x;
    if (blk < 256) {
        int c = blk, h = c >> 5, e = c & 31;
        wT[c * 256 + t] = f2bf(weight[h * 8192 + t * 32 + e]);
    } else {
        int id = blk - 256, h = id >> 1, which = id & 1;
        float s = 0.f;
        for (int e = 0; e < 32; ++e)
            s += weight[h * 8192 + t * 32 + e] * att[h * 64 + which * 32 + e];
        s *= LOG2E;   // scores live in log2 domain (leaky commutes with pos scale)
        (which ? wa2 : wa1)[h * 256 + t] = s;
    }
}

// ---- s1,s2 fp32 exact-score path (s1 = x @ (W@a1)) + x16 bf16 copy ----
__global__ void k_prep_s(const float* __restrict__ x, const float* __restrict__ wa1,
                         const float* __restrict__ wa2, float* __restrict__ s1,
                         float* __restrict__ s2, unsigned short* __restrict__ x16) {
    __shared__ float xs[256];
    int bm = blockIdx.x, t = threadIdx.x;
    float xv = x[bm * 256 + t];
    xs[t] = xv;
    x16[bm * 256 + t] = f2bf(xv);
    __syncthreads();
    int lane16 = t & 15, grp = t >> 4;
    int h = grp >> 1, which = grp & 1;
    const float* wap = (which ? wa2 : wa1) + h * 256;
    float s = 0.f;
    for (int f = lane16; f < 256; f += 16) s += xs[f] * wap[f];
    s += __shfl_xor(s, 8); s += __shfl_xor(s, 4);
    s += __shfl_xor(s, 2); s += __shfl_xor(s, 1);
    if (lane16 == 0) {
        int b = bm >> 10, m = bm & 1023;
        (which ? s2 : s1)[(b * 8 + h) * 1024 + m] = s;
    }
}

// ---- adj (32MB int) -> packed bitmask (1MB), streaming at HBM rate ----
__global__ void k_mask(const int* __restrict__ adj, unsigned* __restrict__ gmask) {
    int t = threadIdx.x, w = t >> 6, l = t & 63;
    int wid = blockIdx.x * 4 + w;
#pragma unroll
    for (int i = 0; i < 4; ++i) {
        int c = wid * 4 + i;
        int val = adj[c * 64 + l];
        unsigned long long mk = __ballot(val > 0);
        if (l == 0) {
            gmask[c * 2]     = (unsigned)mk;
            gmask[c * 2 + 1] = (unsigned)(mk >> 32);
        }
    }
}

// ---- WhT[(b,h,e)][m] bf16 = (x@W)^T via MFMA (A=wT rows c, B=x^T cols m) ----
__global__ void k_wht(const unsigned short* __restrict__ wT,
                      const unsigned short* __restrict__ x16,
                      unsigned short* __restrict__ WhT) {
    int t = threadIdx.x;
    int W = blockIdx.x * 4 + (t >> 6);
    int l = t & 63;
    int b = W >> 8, r = W & 255;
    int c0 = (r >> 4) * 16, m0 = (r & 15) * 64;
    int lrow = l & 15, lk = l >> 4;
    f32x4 acc[4] = {{0,0,0,0},{0,0,0,0},{0,0,0,0},{0,0,0,0}};
    const unsigned short* ap = wT + (c0 + lrow) * 256 + lk * 8;
    const unsigned short* bp = x16 + (b * 1024 + m0 + lrow) * 256 + lk * 8;
    for (int k0 = 0; k0 < 256; k0 += 32) {
        s16x8 af = *(const s16x8*)(ap + k0);
#pragma unroll
        for (int t4 = 0; t4 < 4; ++t4) {
            s16x8 bf = *(const s16x8*)(bp + t4 * 16 * 256 + k0);
            acc[t4] = __builtin_amdgcn_mfma_f32_16x16x32_bf16(af, bf, acc[t4], 0, 0, 0);
        }
    }
#pragma unroll
    for (int t4 = 0; t4 < 4; ++t4)
#pragma unroll
        for (int j = 0; j < 4; ++j) {
            int c = c0 + lk * 4 + j;
            int m = m0 + t4 * 16 + lrow;
            WhT[(b * 256 + c) * 1024 + m] = f2bf(acc[t4][j]);
        }
}

// ---- attention: grid 2048 (b, mtile, hg-pair), 4 waves = 2 heads x 2 n-halves ----
__global__ void __launch_bounds__(256) k_attn(const unsigned* __restrict__ gmask,
                                              const float* __restrict__ s1,
                                              const float* __restrict__ s2,
                                              const unsigned short* __restrict__ WhT,
                                              float* __restrict__ out) {
    __shared__ float s2s[2][1024];
    __shared__ unsigned amaskw[16][33];
    __shared__ float s1s[2][16];
    __shared__ float mxsh[2][16][2];
    __shared__ float accsh[2][64][13];   // pad 13: stride coprime with 32 banks
    int bid = blockIdx.x;
    int o = (bid & 7) * 256 + (bid >> 3);   // XCD swizzle: each XCD owns one b
    int b = o >> 8, r = o & 255;
    int m0 = (r >> 2) * 16, hg = (r & 3) * 2;
    int t = threadIdx.x, w = t >> 6, l = t & 63;
    int hd = w & 1, nh = w >> 1;
    for (int i = t; i < 2048; i += 256) s2s[i >> 10][i & 1023] = s2[b * 8192 + hg * 1024 + i];
    for (int i = t; i < 512; i += 256) amaskw[i >> 5][i & 31] = gmask[(b * 1024 + m0) * 32 + i];
    if (t < 32) s1s[t >> 4][t & 15] = s1[b * 8192 + (hg + (t >> 4)) * 1024 + m0 + (t & 15)];
    __syncthreads();
    int m = l & 15, q = l >> 4;
    int h = hg + hd;
    float s1v = s1s[hd][m];
    int nbase = nh * 512;
    // pass A: masked row-max of s2 over this wave's n-half
    float mxs2 = -3.0e38f;
    for (int n0 = 0; n0 < 512; n0 += 32) {
        unsigned wm8 = amaskw[m][(nbase + n0) >> 5] >> (q * 8);
        int nn = nbase + n0 + q * 8;
        f32x4 svA = *(const f32x4*)&s2s[hd][nn];
        f32x4 svB = *(const f32x4*)&s2s[hd][nn + 4];
#pragma unroll
        for (int u = 0; u < 8; ++u) {
            float sv = (u < 4 ? svA[u] : svB[u - 4]);
            mxs2 = fmaxf(mxs2, ((wm8 >> u) & 1u) ? sv : -3.0e38f);
        }
    }
    mxs2 = fmaxf(mxs2, __shfl_xor(mxs2, 16));
    mxs2 = fmaxf(mxs2, __shfl_xor(mxs2, 32));
    if (l < 16) mxsh[hd][l][nh] = mxs2;
    __syncthreads();
    float mxf = fmaxf(mxsh[hd][m][0], mxsh[hd][m][1]);
    float mxr = s1v + mxf;
    float mx = fmaxf(mxr, ALPHA * mxr);           // exact masked row-max (log2 units)
    float c1 = s1v - mx;
    float c2 = fmaf(ALPHA, s1v, -mx);
    // pass B: P = exp2(max(sv+c1, fma(.2,sv,c2)) | masked) ; PV + rowsum via MFMA
    f32x4 acc0 = {0,0,0,0}, acc1 = {0,0,0,0}, accs = {0,0,0,0};
    s16x8 ones;
#pragma unroll
    for (int u = 0; u < 8; ++u) ones[u] = (short)0x3F80;   // bf16 1.0
    const unsigned short* whb = WhT + (b * 8 + h) * 32768;
    const unsigned short* bp0 = whb + m * 1024 + q * 8 + nbase;
    const unsigned short* bp1 = bp0 + 16 * 1024;
    for (int n0 = 0; n0 < 512; n0 += 32) {
        unsigned wm8 = amaskw[m][(nbase + n0) >> 5] >> (q * 8);
        int nn = nbase + n0 + q * 8;
        f32x4 svA = *(const f32x4*)&s2s[hd][nn];
        f32x4 svB = *(const f32x4*)&s2s[hd][nn + 4];
        float pv[8];
#pragma unroll
        for (int u = 0; u < 8; ++u) {
            float sv = (u < 4 ? svA[u] : svB[u - 4]);
            float a = sv + c1;
            float bb = fmaf(ALPHA, sv, c2);
            float mm = fmaxf(a, bb);                       // leaky(s)-mx, <=~0 if masked
            float arg = ((wm8 >> u) & 1u) ? mm : -3.0e38f; // select BEFORE exp: no inf*0
            pv[u] = __builtin_amdgcn_exp2f(arg);
        }
        u32x4 aw;
#pragma unroll
        for (int p = 0; p < 4; ++p) {
            union { float f; unsigned u; } lo, hi;
            lo.f = pv[2 * p]; hi.f = pv[2 * p + 1];
            aw[p] = __builtin_amdgcn_perm(hi.u, lo.u, 0x07060302u);
        }
        s16x8 af = __builtin_bit_cast(s16x8, aw);
        s16x8 bf0 = *(const s16x8*)(bp0 + n0);
        s16x8 bf1 = *(const s16x8*)(bp1 + n0);
        acc0 = __builtin_amdgcn_mfma_f32_16x16x32_bf16(af, bf0, acc0, 0, 0, 0);
        acc1 = __builtin_amdgcn_mfma_f32_16x16x32_bf16(af, bf1, acc1, 0, 0, 0);
        accs = __builtin_amdgcn_mfma_f32_16x16x32_bf16(af, ones, accs, 0, 0, 0);
    }
    if (nh == 1) {
#pragma unroll
        for (int j = 0; j < 4; ++j) {
            accsh[hd][l][j]     = acc0[j];
            accsh[hd][l][4 + j] = acc1[j];
            accsh[hd][l][8 + j] = accs[j];
        }
    }
    __syncthreads();
    if (nh == 0) {
#pragma unroll
        for (int j = 0; j < 4; ++j) {
            float a0 = acc0[j] + accsh[hd][l][j];
            float a1 = acc1[j] + accsh[hd][l][4 + j];
            float as = accs[j] + accsh[hd][l][8 + j];
            float inv = 1.f / as;
            float v0 = a0 * inv;
            float v1 = a1 * inv;
            v0 = v0 > 0.f ? v0 : __expf(v0) - 1.f;
            v1 = v1 > 0.f ? v1 : __expf(v1) - 1.f;
            int mrow = q * 4 + j;
            float* op = &out[(b * 1024 + m0 + mrow) * 256 + h * 32];
            op[m] = v0;
            op[16 + m] = v1;
        }
    }
}

extern "C" void kernel_launch(void* const* d_in, const int* in_sizes, int n_in,
                              void* d_out, int out_size, void* d_ws, size_t ws_size,
                              hipStream_t stream) {
    const float* x      = (const float*)d_in[0];
    const int*   adj    = (const int*)d_in[1];
    const float* weight = (const float*)d_in[2];
    const float* att    = (const float*)d_in[3];

    char* ws = (char*)d_ws;
    unsigned short* wT  = (unsigned short*)(ws);             // 128K
    unsigned short* x16 = (unsigned short*)(ws + 131072);    // 4M
    unsigned short* WhT = (unsigned short*)(ws + 4325376);   // 4M
    float* s1  = (float*)(ws + 8519680);                     // 256K
    float* s2  = (float*)(ws + 8781824);                     // 256K
    float* wa1 = (float*)(ws + 9043968);                     // 8K
    float* wa2 = (float*)(ws + 9052160);                     // 8K
    unsigned* gmask = (unsigned*)(ws + 9060352);             // 1M
    float* out = (float*)d_out;

    k_prep_w<<<272, 256, 0, stream>>>(weight, att, wT, wa1, wa2);
    k_prep_s<<<8192, 256, 0, stream>>>(x, wa1, wa2, s1, s2, x16);
    k_mask<<<8192, 256, 0, stream>>>(adj, gmask);
    k_wht<<<512, 256, 0, stream>>>(wT, x16, WhT);
    k_attn<<<2048, 256, 0, stream>>>(gmask, s1, s2, WhT, out);
}